// Round 12
// baseline (1114.868 us; speedup 1.0000x reference)
//
#include <hip/hip_runtime.h>
#include <hip/hip_cooperative_groups.h>
#include <math.h>

namespace cg = cooperative_groups;

#define BATCH 8
#define NPTS 2048
#define MPTS 2048
#define TPB 256                       // 4 waves
#define KC 8                          // columns per thread: 2048/256

// ---- cooperative config: 512 blocks = 2/CU -> co-resident at VGPR<=256 ----
#define RPB_C 32
#define CHUNKS_C (NPTS/RPB_C)         // 64
#define NBLK_C (BATCH*CHUNKS_C)       // 512
#define NRND_C (RPB_C/2)              // 16 rounds, 2 rows each

// ---- fallback (R8, proven) config ----
#define RPB_F 16
#define CHUNKS_F (NPTS/RPB_F)         // 128
#define NBLK_F (BATCH*CHUNKS_F)       // 1024
#define NRND_F (RPB_F/2)              // 8

// Persistent state (re-initialized every kernel_launch -> deterministic).
__device__ float  g_remainl[BATCH*NPTS];
__device__ float  g_s[BATCH*NPTS];
__device__ float  g_rbuf[2][BATCH*MPTS];
__device__ float  g_cbuf[3][BATCH*MPTS];
__device__ float4 g_gt4[BATCH*MPTS];   // (x, y, z, |c|^2)
__device__ float4 g_gen4[BATCH*NPTS];  // (-2x, -2y, -2z, |g|^2)
__device__ float  g_cost;

#if __has_builtin(__builtin_amdgcn_exp2f)
#define EXP2(x) __builtin_amdgcn_exp2f(x)
#else
#define EXP2(x) exp2f(x)
#endif
#if __has_builtin(__builtin_amdgcn_sqrtf)
#define FSQRT(x) __builtin_amdgcn_sqrtf(x)
#else
#define FSQRT(x) sqrtf(x)
#endif
#if __has_builtin(__builtin_amdgcn_rcpf)
#define RCP(x) __builtin_amdgcn_rcpf(x)
#else
#define RCP(x) (1.0f/(x))
#endif

template<int CTRL>
__device__ __forceinline__ float dpp_add(float x) {
  const int y = __builtin_amdgcn_update_dpp(0, __float_as_int(x),
                                            CTRL, 0xF, 0xF, true);
  return x + __int_as_float(y);
}
__device__ __forceinline__ void wsum_step4(float& a, float& b, float& c, float& d) {
  a = dpp_add<0xB1>(a);  b = dpp_add<0xB1>(b);
  c = dpp_add<0xB1>(c);  d = dpp_add<0xB1>(d);
  a = dpp_add<0x4E>(a);  b = dpp_add<0x4E>(b);
  c = dpp_add<0x4E>(c);  d = dpp_add<0x4E>(d);
  a = dpp_add<0x141>(a); b = dpp_add<0x141>(b);
  c = dpp_add<0x141>(c); d = dpp_add<0x141>(d);
  a = dpp_add<0x140>(a); b = dpp_add<0x140>(b);
  c = dpp_add<0x140>(c); d = dpp_add<0x140>(d);
  a += __shfl_xor(a, 16); b += __shfl_xor(b, 16);
  c += __shfl_xor(c, 16); d += __shfl_xor(d, 16);
  a += __shfl_xor(a, 32); b += __shfl_xor(b, 32);
  c += __shfl_xor(c, 32); d += __shfl_xor(d, 32);
}
__device__ __forceinline__ void wsum_step2(float& a, float& b) {
  a = dpp_add<0xB1>(a);  b = dpp_add<0xB1>(b);
  a = dpp_add<0x4E>(a);  b = dpp_add<0x4E>(b);
  a = dpp_add<0x141>(a); b = dpp_add<0x141>(b);
  a = dpp_add<0x140>(a); b = dpp_add<0x140>(b);
  a += __shfl_xor(a, 16); b += __shfl_xor(b, 16);
  a += __shfl_xor(a, 32); b += __shfl_xor(b, 32);
}
__device__ __forceinline__ float wsum_step1(float a) {
  a = dpp_add<0xB1>(a); a = dpp_add<0x4E>(a);
  a = dpp_add<0x141>(a); a = dpp_add<0x140>(a);
  a += __shfl_xor(a, 16); a += __shfl_xor(a, 32);
  return a;
}

#define D2(rd, k) fmaf(rd.x, cx[k], fmaf(rd.y, cy[k],                      \
                   fmaf(rd.z, cz[k], rd.w + rc2[k])))

__global__ __launch_bounds__(256) void k_init(const float* __restrict__ gen,
                                              const float* __restrict__ gt) {
  const int i = blockIdx.x*256 + threadIdx.x;   // 64 x 256 = 16384 = B*N
  g_cbuf[0][i] = 0.f;
  g_cbuf[1][i] = 0.f;
  g_rbuf[0][i] = 1.f;
  const float tx = gt[i*3], ty = gt[i*3+1], tz = gt[i*3+2];
  g_gt4[i] = make_float4(tx, ty, tz, tx*tx + ty*ty + tz*tz);
  const float px = gen[i*3], py = gen[i*3+1], pz = gen[i*3+2];
  g_gen4[i] = make_float4(-2.f*px, -2.f*py, -2.f*pz, px*px + py*py + pz*pz);
  if (i == 0) g_cost = 0.f;
}

// ======================= cooperative persistent path =======================
__global__ __launch_bounds__(TPB) void k_all(float* __restrict__ out, float c0) {
  cg::grid_group grid = cg::this_grid();
  const int blk = blockIdx.x, b = blk >> 6, chunk = blk & (CHUNKS_C-1);
  const int t = threadIdx.x, wave = t >> 6, lane = t & 63;
  const int rowbase = b*NPTS + chunk*RPB_C;
  __shared__ float4 rowdat[RPB_C];
  __shared__ float  sc_s[2][RPB_C], rl_s[2][RPB_C];
  __shared__ float4 red[2][4];
  __shared__ float  cred[4];

  float cx[KC], cy[KC], cz[KC], rc2[KC], rr[KC], pp[KC];
  #pragma unroll
  for (int k = 0; k < KC; ++k) {
    const float4 q = g_gt4[b*MPTS + t + TPB*k];
    cx[k] = q.x; cy[k] = q.y; cz[k] = q.z; rc2[k] = q.w;
    rr[k] = 1.0f;
  }
  if (t < RPB_C) {
    rowdat[t] = g_gen4[rowbase + t];
    rl_s[0][t] = 1.0f;
  }
  __syncthreads();

  float colacc[KC];
  #pragma unroll
  for (int k = 0; k < KC; ++k) colacc[k] = 0.f;
  float costacc = 0.f;
  float c1 = c0;

  const float* p0 = g_cbuf[0];
  float*       p1 = g_cbuf[1];
  float*       p2 = g_cbuf[2];

  // ---- A0: level 0 (remainl = remainr = 1) ----
  #pragma unroll 1
  for (int rnd = 0; rnd < NRND_C; ++rnd) {
    const float4 rd0 = rowdat[2*rnd], rd1 = rowdat[2*rnd+1];
    float w0[KC], w1[KC];
    float s1a = 0.f, s1b = 0.f;
    #pragma unroll
    for (int k = 0; k < KC; ++k) {
      const float ea = EXP2(c1*D2(rd0, k));
      const float eb = EXP2(c1*D2(rd1, k));
      w0[k] = ea; s1a += ea;
      w1[k] = eb; s1b += eb;
    }
    wsum_step2(s1a, s1b);
    if (lane == 0) red[rnd&1][wave] = make_float4(s1a, s1b, 0.f, 0.f);
    __syncthreads();
    const float4 v0 = red[rnd&1][0], v1 = red[rnd&1][1];
    const float4 v2 = red[rnd&1][2], v3 = red[rnd&1][3];
    const float scn0 = RCP(v0.x+v1.x+v2.x+v3.x + 1e-9f);
    const float scn1 = RCP(v0.y+v1.y+v2.y+v3.y + 1e-9f);
    if (t == 0) { sc_s[0][2*rnd] = scn0; sc_s[0][2*rnd+1] = scn1; }
    #pragma unroll
    for (int k = 0; k < KC; ++k)
      colacc[k] = fmaf(w0[k], scn0, fmaf(w1[k], scn1, colacc[k]));
  }
  #pragma unroll
  for (int k = 0; k < KC; ++k) {
    atomicAdd(&g_cbuf[0][b*MPTS + t + TPB*k], colacc[k]);
    colacc[k] = 0.f;
  }
  __threadfence();
  grid.sync();

  // ---- CA levels 0..7 ----
  #pragma unroll 1
  for (int l = 0; l < 8; ++l) {
    const float cq = c1 * 0.25f;
    const int sp = l & 1;
    #pragma unroll
    for (int k = 0; k < KC; ++k) {
      const int m = b*MPTS + t + TPB*k;
      const float cs = p0[m];
      const float ratio = fminf(rr[k] / (cs + 1e-9f), 1.0f);
      pp[k] = rr[k]*ratio;
      rr[k] = fmaxf(rr[k] - cs*ratio, 0.0f);
      if (chunk == 0) p2[m] = 0.0f;
    }
    #pragma unroll 1
    for (int rnd = 0; rnd < NRND_C; ++rnd) {
      const int r0 = 2*rnd, r1 = r0 + 1;
      const float4 rd0 = rowdat[r0], rd1 = rowdat[r1];
      float w0[KC], w1[KC];
      float s1a = 0.f, rsa = 0.f, s2a = 0.f;
      float s1b = 0.f, rsb = 0.f, s2b = 0.f;
      #pragma unroll
      for (int k = 0; k < KC; ++k) {
        const float d2a = D2(rd0, k), d2b = D2(rd1, k);
        const float eqa = EXP2(cq*d2a), eqb = EXP2(cq*d2b);
        const float q2a = eqa*eqa, q2b = eqb*eqb;
        const float e1a = q2a*q2a, e1b = q2b*q2b;   // e1 = eq^4 (c1 = 4cq)
        const float wqa = eqa*rr[k], wqb = eqb*rr[k];
        w0[k] = wqa; rsa += wqa;
        w1[k] = wqb; rsb += wqb;
        const float ua = e1a*pp[k], ub = e1b*pp[k];
        s1a += ua; s1b += ub;
        s2a = fmaf(ua, FSQRT(fmaxf(d2a, 1e-20f)), s2a);
        s2b = fmaf(ub, FSQRT(fmaxf(d2b, 1e-20f)), s2b);
      }
      costacc = fmaf(sc_s[sp][r0], s2a, costacc);
      costacc = fmaf(sc_s[sp][r1], s2b, costacc);
      wsum_step4(s1a, rsa, s1b, rsb);
      if (lane == 0) red[rnd&1][wave] = make_float4(s1a, rsa, s1b, rsb);
      __syncthreads();
      const float4 v0 = red[rnd&1][0], v1 = red[rnd&1][1];
      const float4 v2 = red[rnd&1][2], v3 = red[rnd&1][3];
      const float s1t0 = v0.x+v1.x+v2.x+v3.x;
      const float rst0 = v0.y+v1.y+v2.y+v3.y;
      const float s1t1 = v0.z+v1.z+v2.z+v3.z;
      const float rst1 = v0.w+v1.w+v2.w+v3.w;
      const float rl0 = fmaxf(rl_s[sp][r0] - sc_s[sp][r0]*s1t0, 0.0f);
      const float rl1 = fmaxf(rl_s[sp][r1] - sc_s[sp][r1]*s1t1, 0.0f);
      const float scn0 = rl0 * RCP(rst0 + 1e-9f);
      const float scn1 = rl1 * RCP(rst1 + 1e-9f);
      if (t == 0) {
        sc_s[sp^1][r0] = scn0; sc_s[sp^1][r1] = scn1;
        rl_s[sp^1][r0] = rl0;  rl_s[sp^1][r1] = rl1;
      }
      #pragma unroll
      for (int k = 0; k < KC; ++k)
        colacc[k] = fmaf(w0[k], scn0, fmaf(w1[k], scn1, colacc[k]));
    }
    #pragma unroll
    for (int k = 0; k < KC; ++k) {
      atomicAdd(&p1[b*MPTS + t + TPB*k], colacc[k]);
      colacc[k] = 0.f;
    }
    c1 = cq;
    const float* tp = p0; p0 = p1; p1 = p2; p2 = (float*)tp;
    __threadfence();
    grid.sync();
  }

  // ---- CA-LAST (l = 8): next level coeff 0 -> eq = 1 ----
  {
    const int sp = 0;
    #pragma unroll
    for (int k = 0; k < KC; ++k) {
      const int m = b*MPTS + t + TPB*k;
      const float cs = p0[m];
      const float ratio = fminf(rr[k] / (cs + 1e-9f), 1.0f);
      pp[k] = rr[k]*ratio;
      rr[k] = fmaxf(rr[k] - cs*ratio, 0.0f);
    }
    #pragma unroll 1
    for (int rnd = 0; rnd < NRND_C; ++rnd) {
      const int r0 = 2*rnd, r1 = r0 + 1;
      const float4 rd0 = rowdat[r0], rd1 = rowdat[r1];
      float s1a = 0.f, rsa = 0.f, s2a = 0.f;
      float s1b = 0.f, rsb = 0.f, s2b = 0.f;
      #pragma unroll
      for (int k = 0; k < KC; ++k) {
        const float d2a = D2(rd0, k), d2b = D2(rd1, k);
        const float e1a = EXP2(c1*d2a), e1b = EXP2(c1*d2b);
        rsa += rr[k]; rsb += rr[k];
        const float ua = e1a*pp[k], ub = e1b*pp[k];
        s1a += ua; s1b += ub;
        s2a = fmaf(ua, FSQRT(fmaxf(d2a, 1e-20f)), s2a);
        s2b = fmaf(ub, FSQRT(fmaxf(d2b, 1e-20f)), s2b);
      }
      costacc = fmaf(sc_s[sp][r0], s2a, costacc);
      costacc = fmaf(sc_s[sp][r1], s2b, costacc);
      wsum_step4(s1a, rsa, s1b, rsb);
      if (lane == 0) red[rnd&1][wave] = make_float4(s1a, rsa, s1b, rsb);
      __syncthreads();
      const float4 v0 = red[rnd&1][0], v1 = red[rnd&1][1];
      const float4 v2 = red[rnd&1][2], v3 = red[rnd&1][3];
      const float s1t0 = v0.x+v1.x+v2.x+v3.x;
      const float rst0 = v0.y+v1.y+v2.y+v3.y;
      const float s1t1 = v0.z+v1.z+v2.z+v3.z;
      const float rst1 = v0.w+v1.w+v2.w+v3.w;
      const float rl0 = fmaxf(rl_s[sp][r0] - sc_s[sp][r0]*s1t0, 0.0f);
      const float rl1 = fmaxf(rl_s[sp][r1] - sc_s[sp][r1]*s1t1, 0.0f);
      const float scn0 = rl0 * RCP(rst0 + 1e-9f);
      const float scn1 = rl1 * RCP(rst1 + 1e-9f);
      if (t == 0) { sc_s[1][r0] = scn0; sc_s[1][r1] = scn1; }
      #pragma unroll
      for (int k = 0; k < KC; ++k)
        colacc[k] = fmaf(rr[k], scn0 + scn1, colacc[k]);
    }
    #pragma unroll
    for (int k = 0; k < KC; ++k)
      atomicAdd(&p1[b*MPTS + t + TPB*k], colacc[k]);
    __threadfence();
    grid.sync();
  }

  // ---- C9: level 9 (coeff 0 -> weight = p) ----
  {
    #pragma unroll
    for (int k = 0; k < KC; ++k) {
      const int m = b*MPTS + t + TPB*k;
      const float cs = p1[m];
      const float ratio = fminf(rr[k] / (cs + 1e-9f), 1.0f);
      pp[k] = rr[k]*ratio;
    }
    #pragma unroll 1
    for (int r = 0; r < RPB_C; ++r) {
      const float4 rd = rowdat[r];
      float s2 = 0.f;
      #pragma unroll
      for (int k = 0; k < KC; ++k)
        s2 = fmaf(pp[k], FSQRT(fmaxf(D2(rd, k), 1e-20f)), s2);
      costacc = fmaf(sc_s[1][r], s2, costacc);
    }
  }

  costacc = wsum_step1(costacc);
  if (lane == 0) cred[wave] = costacc;
  __syncthreads();
  if (t == 0)
    atomicAdd(&g_cost, cred[0] + cred[1] + cred[2] + cred[3]);
  __threadfence();
  grid.sync();
  if (blk == 0 && t == 0)
    out[0] = g_cost * (1.0f / (float)(BATCH*NPTS));
}

// ===================== fallback path (R8 exact, proven) =====================
__global__ __launch_bounds__(TPB) void k_a0(float c1) {
  const int blk = blockIdx.x, b = blk >> 7, chunk = blk & (CHUNKS_F-1);
  const int t = threadIdx.x, wave = t >> 6, lane = t & 63;
  const int rowbase = b*NPTS + chunk*RPB_F;
  __shared__ float4 rowdat[RPB_F];
  __shared__ float2 red[2][4];
  float cx[KC], cy[KC], cz[KC], rc2[KC];
  #pragma unroll
  for (int k = 0; k < KC; ++k) {
    const float4 q = g_gt4[b*MPTS + t + TPB*k];
    cx[k] = q.x; cy[k] = q.y; cz[k] = q.z; rc2[k] = q.w;
  }
  if (t < RPB_F) {
    rowdat[t] = g_gen4[rowbase + t];
    g_remainl[rowbase + t] = 1.0f;
  }
  __syncthreads();
  float colacc[KC];
  #pragma unroll
  for (int k = 0; k < KC; ++k) colacc[k] = 0.f;
  #pragma unroll 1
  for (int rr = 0; rr < NRND_F; ++rr) {
    const float4 rd0 = rowdat[2*rr+0];
    const float4 rd1 = rowdat[2*rr+1];
    float w0[KC], w1[KC];
    float s1a = 0.f, s1b = 0.f;
    #pragma unroll
    for (int k = 0; k < KC; ++k) {
      const float ea = EXP2(c1*D2(rd0, k));
      const float eb = EXP2(c1*D2(rd1, k));
      w0[k] = ea; s1a += ea;
      w1[k] = eb; s1b += eb;
    }
    wsum_step2(s1a, s1b);
    if (lane == 0) red[rr&1][wave] = make_float2(s1a, s1b);
    __syncthreads();
    const float2 v0 = red[rr&1][0], v1 = red[rr&1][1];
    const float2 v2 = red[rr&1][2], v3 = red[rr&1][3];
    const float scn0 = RCP(v0.x+v1.x+v2.x+v3.x + 1e-9f);
    const float scn1 = RCP(v0.y+v1.y+v2.y+v3.y + 1e-9f);
    if (t == 0) {
      g_s[rowbase + 2*rr + 0] = scn0;
      g_s[rowbase + 2*rr + 1] = scn1;
    }
    #pragma unroll
    for (int k = 0; k < KC; ++k)
      colacc[k] = fmaf(w0[k], scn0, fmaf(w1[k], scn1, colacc[k]));
  }
  #pragma unroll
  for (int k = 0; k < KC; ++k)
    atomicAdd(&g_cbuf[0][b*MPTS + t + TPB*k], colacc[k]);
}

template<bool LAST>
__global__ __launch_bounds__(TPB) void k_ca(float c1, float cq, int l) {
  const int blk = blockIdx.x, b = blk >> 7, chunk = blk & (CHUNKS_F-1);
  const int t = threadIdx.x, wave = t >> 6, lane = t & 63;
  const int rowbase = b*NPTS + chunk*RPB_F;
  const float* __restrict__ cs_in = g_cbuf[l % 3];
  float* __restrict__ cs_out  = g_cbuf[(l+1) % 3];
  float* __restrict__ cs_zero = g_cbuf[(l+2) % 3];
  const float* __restrict__ rr_in = g_rbuf[l & 1];
  float* __restrict__ rr_out = g_rbuf[(l+1) & 1];
  __shared__ float4 rowdat[RPB_F];
  __shared__ float  sc_s[RPB_F], rl_s[RPB_F];
  __shared__ float4 red[2][4];
  __shared__ float  cred[4];
  float cx[KC], cy[KC], cz[KC], rc2[KC], pp[KC], rrn[KC];
  #pragma unroll
  for (int k = 0; k < KC; ++k) {
    const int m = b*MPTS + t + TPB*k;
    const float4 q = g_gt4[m];
    cx[k] = q.x; cy[k] = q.y; cz[k] = q.z; rc2[k] = q.w;
    const float cs = cs_in[m], rrv = rr_in[m];
    const float ratio = fminf(rrv / (cs + 1e-9f), 1.0f);
    pp[k]  = rrv*ratio;
    rrn[k] = fmaxf(rrv - cs*ratio, 0.0f);
    if (chunk == 0) { rr_out[m] = rrn[k]; cs_zero[m] = 0.0f; }
  }
  if (t < RPB_F) {
    rowdat[t] = g_gen4[rowbase + t];
    sc_s[t] = g_s[rowbase + t];
    rl_s[t] = g_remainl[rowbase + t];
  }
  __syncthreads();
  float colacc[KC];
  #pragma unroll
  for (int k = 0; k < KC; ++k) colacc[k] = 0.f;
  float costacc = 0.f;
  #pragma unroll 1
  for (int rr = 0; rr < NRND_F; ++rr) {
    const int r0 = 2*rr, r1 = r0 + 1;
    const float4 rd0 = rowdat[r0];
    const float4 rd1 = rowdat[r1];
    float w0[KC], w1[KC];
    float s1a = 0.f, rsa = 0.f, s2a = 0.f;
    float s1b = 0.f, rsb = 0.f, s2b = 0.f;
    #pragma unroll
    for (int k = 0; k < KC; ++k) {
      {
        const float d2 = D2(rd0, k);
        float e1, wq;
        if (LAST) { e1 = EXP2(c1*d2); wq = rrn[k]; }
        else { const float eq = EXP2(cq*d2); const float e2 = eq*eq;
               e1 = e2*e2; wq = eq*rrn[k]; }
        w0[k] = wq; rsa += wq;
        const float u = e1*pp[k];
        s1a += u;
        s2a = fmaf(u, FSQRT(fmaxf(d2, 1e-20f)), s2a);
      }
      {
        const float d2 = D2(rd1, k);
        float e1, wq;
        if (LAST) { e1 = EXP2(c1*d2); wq = rrn[k]; }
        else { const float eq = EXP2(cq*d2); const float e2 = eq*eq;
               e1 = e2*e2; wq = eq*rrn[k]; }
        w1[k] = wq; rsb += wq;
        const float u = e1*pp[k];
        s1b += u;
        s2b = fmaf(u, FSQRT(fmaxf(d2, 1e-20f)), s2b);
      }
    }
    costacc = fmaf(sc_s[r0], s2a, costacc);
    costacc = fmaf(sc_s[r1], s2b, costacc);
    wsum_step4(s1a, rsa, s1b, rsb);
    if (lane == 0) red[rr&1][wave] = make_float4(s1a, rsa, s1b, rsb);
    __syncthreads();
    const float4 v0 = red[rr&1][0], v1 = red[rr&1][1];
    const float4 v2 = red[rr&1][2], v3 = red[rr&1][3];
    const float s1t0 = v0.x+v1.x+v2.x+v3.x;
    const float rst0 = v0.y+v1.y+v2.y+v3.y;
    const float s1t1 = v0.z+v1.z+v2.z+v3.z;
    const float rst1 = v0.w+v1.w+v2.w+v3.w;
    const float rl0 = fmaxf(rl_s[r0] - sc_s[r0]*s1t0, 0.0f);
    const float rl1 = fmaxf(rl_s[r1] - sc_s[r1]*s1t1, 0.0f);
    const float scn0 = rl0 * RCP(rst0 + 1e-9f);
    const float scn1 = rl1 * RCP(rst1 + 1e-9f);
    if (t == 0) {
      g_remainl[rowbase + r0] = rl0;
      g_remainl[rowbase + r1] = rl1;
      g_s[rowbase + r0] = scn0;
      g_s[rowbase + r1] = scn1;
    }
    #pragma unroll
    for (int k = 0; k < KC; ++k)
      colacc[k] = fmaf(w0[k], scn0, fmaf(w1[k], scn1, colacc[k]));
  }
  #pragma unroll
  for (int k = 0; k < KC; ++k)
    atomicAdd(&cs_out[b*MPTS + t + TPB*k], colacc[k]);
  costacc = wsum_step1(costacc);
  if (lane == 0) cred[wave] = costacc;
  __syncthreads();
  if (t == 0)
    atomicAdd(&g_cost, cred[0] + cred[1] + cred[2] + cred[3]);
}

__global__ __launch_bounds__(TPB) void k_c_last() {
  const int blk = blockIdx.x, b = blk >> 7, chunk = blk & (CHUNKS_F-1);
  const int t = threadIdx.x, wave = t >> 6, lane = t & 63;
  const int rowbase = b*NPTS + chunk*RPB_F;
  const float* __restrict__ cs_in = g_cbuf[0];
  const float* __restrict__ rr_in = g_rbuf[1];
  __shared__ float4 rowdat[RPB_F];
  __shared__ float  sc_s[RPB_F];
  __shared__ float  cred[4];
  float cx[KC], cy[KC], cz[KC], rc2[KC], pp[KC];
  #pragma unroll
  for (int k = 0; k < KC; ++k) {
    const int m = b*MPTS + t + TPB*k;
    const float4 q = g_gt4[m];
    cx[k] = q.x; cy[k] = q.y; cz[k] = q.z; rc2[k] = q.w;
    const float cs = cs_in[m], rrv = rr_in[m];
    const float ratio = fminf(rrv / (cs + 1e-9f), 1.0f);
    pp[k] = rrv*ratio;
  }
  if (t < RPB_F) {
    rowdat[t] = g_gen4[rowbase + t];
    sc_s[t] = g_s[rowbase + t];
  }
  __syncthreads();
  float costacc = 0.f;
  #pragma unroll 1
  for (int r = 0; r < RPB_F; ++r) {
    const float4 rd = rowdat[r];
    float s2 = 0.f;
    #pragma unroll
    for (int k = 0; k < KC; ++k)
      s2 = fmaf(pp[k], FSQRT(fmaxf(D2(rd, k), 1e-20f)), s2);
    costacc = fmaf(sc_s[r], s2, costacc);
  }
  costacc = wsum_step1(costacc);
  if (lane == 0) cred[wave] = costacc;
  __syncthreads();
  if (t == 0)
    atomicAdd(&g_cost, cred[0] + cred[1] + cred[2] + cred[3]);
}

__global__ void k_final(float* __restrict__ out) {
  out[0] = g_cost * (1.0f / (float)(BATCH*NPTS));
}

extern "C" void kernel_launch(void* const* d_in, const int* in_sizes, int n_in,
                              void* d_out, int out_size, void* d_ws, size_t ws_size,
                              hipStream_t stream) {
  const float* gen = (const float*)d_in[0];   // pc_gen [8,2048,3] f32
  const float* gt  = (const float*)d_in[1];   // pc_gt  [8,2048,3] f32
  float* out = (float*)d_out;

  k_init<<<64, 256, 0, stream>>>(gen, gt);

  float c0 = (float)(-16384.0 * 1.4426950408889634);   // level0 * log2(e)
  void* args[] = { (void*)&out, (void*)&c0 };
  hipError_t ret = hipLaunchCooperativeKernel((void*)k_all, dim3(NBLK_C),
                                              dim3(TPB), args, 0, stream);
  if (ret != hipSuccess) {
    // fallback: proven multi-launch sequence (identical math)
    const double L[10] = {-16384.0, -4096.0, -1024.0, -256.0, -64.0,
                          -16.0, -4.0, -1.0, -0.25, 0.0};
    float c[10];
    for (int i = 0; i < 10; ++i) c[i] = (float)(L[i] * 1.4426950408889634);
    k_a0<<<NBLK_F, TPB, 0, stream>>>(c[0]);
    for (int l = 0; l < 8; ++l)
      k_ca<false><<<NBLK_F, TPB, 0, stream>>>(c[l], c[l+1], l);
    k_ca<true><<<NBLK_F, TPB, 0, stream>>>(c[8], 0.f, 8);
    k_c_last<<<NBLK_F, TPB, 0, stream>>>();
    k_final<<<1, 1, 0, stream>>>(out);
  }
}

// Round 13
// 398.718 us; speedup vs baseline: 2.7961x; 2.7961x over previous
//
#include <hip/hip_runtime.h>
#include <math.h>

#define BATCH 8
#define NPTS 2048
#define MPTS 2048
#define TPB 512                       // 8 waves
#define RPB 16                        // rows per block
#define KC 4                          // columns per thread: 2048/512
#define NRND 8                        // 2 rows per round
#define CHUNKS (NPTS/RPB)             // 128
#define NBLK (BATCH*CHUNKS)           // 1024

// Persistent state (re-initialized every kernel_launch -> deterministic).
// colsum rotation: level l reads g_cbuf[l%3], accumulates into g_cbuf[(l+1)%3],
// zeroes g_cbuf[(l+2)%3]. remainr ping-pongs g_rbuf[l&1] -> g_rbuf[(l+1)&1].
// rr/zero global writes gated to chunk==0 (identical values across blocks).
__device__ float  g_remainl[BATCH*NPTS];
__device__ float  g_s[BATCH*NPTS];
__device__ float  g_rbuf[2][BATCH*MPTS];
__device__ float  g_cbuf[3][BATCH*MPTS];
__device__ float4 g_gt4[BATCH*MPTS];   // (x, y, z, |c|^2)
__device__ float4 g_gen4[BATCH*NPTS];  // (-2x, -2y, -2z, |g|^2)
__device__ float  g_cost;

#if __has_builtin(__builtin_amdgcn_exp2f)
#define EXP2(x) __builtin_amdgcn_exp2f(x)
#else
#define EXP2(x) exp2f(x)
#endif
#if __has_builtin(__builtin_amdgcn_sqrtf)
#define FSQRT(x) __builtin_amdgcn_sqrtf(x)
#else
#define FSQRT(x) sqrtf(x)
#endif
#if __has_builtin(__builtin_amdgcn_rcpf)
#define RCP(x) __builtin_amdgcn_rcpf(x)
#else
#define RCP(x) (1.0f/(x))
#endif

template<int CTRL>
__device__ __forceinline__ float dpp_add(float x) {
  const int y = __builtin_amdgcn_update_dpp(0, __float_as_int(x),
                                            CTRL, 0xF, 0xF, true);
  return x + __int_as_float(y);
}
// 4 DPP steps -> every lane holds its 16-lane group's sum (lanes 0/16/32/48
// act as group leaders). Pure VALU, no ds ops.
__device__ __forceinline__ void dpp16_4(float& a, float& b, float& c, float& d) {
  a = dpp_add<0xB1>(a);  b = dpp_add<0xB1>(b);   // quad xor1
  c = dpp_add<0xB1>(c);  d = dpp_add<0xB1>(d);
  a = dpp_add<0x4E>(a);  b = dpp_add<0x4E>(b);   // quad xor2
  c = dpp_add<0x4E>(c);  d = dpp_add<0x4E>(d);
  a = dpp_add<0x141>(a); b = dpp_add<0x141>(b);  // half-row mirror
  c = dpp_add<0x141>(c); d = dpp_add<0x141>(d);
  a = dpp_add<0x140>(a); b = dpp_add<0x140>(b);  // row mirror
  c = dpp_add<0x140>(c); d = dpp_add<0x140>(d);
}
__device__ __forceinline__ void dpp16_2(float& a, float& b) {
  a = dpp_add<0xB1>(a);  b = dpp_add<0xB1>(b);
  a = dpp_add<0x4E>(a);  b = dpp_add<0x4E>(b);
  a = dpp_add<0x141>(a); b = dpp_add<0x141>(b);
  a = dpp_add<0x140>(a); b = dpp_add<0x140>(b);
}
__device__ __forceinline__ float wsum_step1(float a) {
  a = dpp_add<0xB1>(a); a = dpp_add<0x4E>(a);
  a = dpp_add<0x141>(a); a = dpp_add<0x140>(a);
  a += __shfl_xor(a, 16); a += __shfl_xor(a, 32);
  return a;
}

#define D2(rd, k) fmaf(rd.x, cx[k], fmaf(rd.y, cy[k],                      \
                   fmaf(rd.z, cz[k], rd.w + rc2[k])))

// init + point prep (SoA float4 with precomputed norms).
__global__ __launch_bounds__(256) void k_init(const float* __restrict__ gen,
                                              const float* __restrict__ gt) {
  const int i = blockIdx.x*256 + threadIdx.x;   // 64 x 256 = 16384 = B*N
  g_cbuf[0][i] = 0.f;
  g_cbuf[1][i] = 0.f;
  g_rbuf[0][i] = 1.f;
  const float tx = gt[i*3], ty = gt[i*3+1], tz = gt[i*3+2];
  g_gt4[i] = make_float4(tx, ty, tz, tx*tx + ty*ty + tz*tz);
  const float px = gen[i*3], py = gen[i*3+1], pz = gen[i*3+2];
  g_gen4[i] = make_float4(-2.f*px, -2.f*py, -2.f*pz, px*px + py*py + pz*pz);
  if (i == 0) g_cost = 0.f;
}

// A-part of level 0 (remainl = remainr = 1): computes s(0), colsum(0).
// Cross-wave reduce: 4-step DPP to 16-lane sums, leader lanes atomicAdd into
// a triple-buffered LDS accumulator (zero/add/read in barrier-separated
// windows), consume = broadcast scalar LDS reads.
__global__ __launch_bounds__(TPB) void k_a0(float c1) {
  const int blk = blockIdx.x, b = blk >> 7, chunk = blk & (CHUNKS-1);
  const int t = threadIdx.x, lane = t & 63, wave = t >> 6;
  const int rowbase = b*NPTS + chunk*RPB;
  __shared__ float4 rowdat[RPB];
  __shared__ float  redf[3][4];
  float cx[KC], cy[KC], cz[KC], rc2[KC];
  #pragma unroll
  for (int k = 0; k < KC; ++k) {
    const float4 q = g_gt4[b*MPTS + t + TPB*k];
    cx[k] = q.x; cy[k] = q.y; cz[k] = q.z; rc2[k] = q.w;
  }
  if (t < RPB) {
    rowdat[t] = g_gen4[rowbase + t];
    g_remainl[rowbase + t] = 1.0f;
  }
  if (t < 12) ((float*)redf)[t] = 0.f;
  __syncthreads();
  float colacc[KC] = {0.f, 0.f, 0.f, 0.f};
  float w0[KC], w1[KC];
  // round 0 element work
  {
    const float4 rd0 = rowdat[0], rd1 = rowdat[1];
    float s1a = 0.f, s1b = 0.f;
    #pragma unroll
    for (int k = 0; k < KC; ++k) {
      const float ea = EXP2(c1*D2(rd0, k));
      const float eb = EXP2(c1*D2(rd1, k));
      w0[k] = ea; s1a += ea;
      w1[k] = eb; s1b += eb;
    }
    dpp16_2(s1a, s1b);
    if ((lane & 15) == 0) {
      atomicAdd(&redf[0][0], s1a);
      atomicAdd(&redf[0][1], s1b);
    }
  }
  #pragma unroll 1
  for (int r = 0; r < NRND; ++r) {
    __syncthreads();
    const float s1t0 = redf[r % 3][0];
    const float s1t1 = redf[r % 3][1];
    if (t < 4) redf[(r + 2) % 3][t] = 0.f;
    const float scn0 = RCP(s1t0 + 1e-9f);   // remainl = 1
    const float scn1 = RCP(s1t1 + 1e-9f);
    if (t == 0) {
      g_s[rowbase + 2*r + 0] = scn0;
      g_s[rowbase + 2*r + 1] = scn1;
    }
    #pragma unroll
    for (int k = 0; k < KC; ++k)
      colacc[k] = fmaf(w0[k], scn0, fmaf(w1[k], scn1, colacc[k]));
    if (r + 1 < NRND) {
      const float4 rd0 = rowdat[2*r+2], rd1 = rowdat[2*r+3];
      float s1a = 0.f, s1b = 0.f;
      #pragma unroll
      for (int k = 0; k < KC; ++k) {
        const float ea = EXP2(c1*D2(rd0, k));
        const float eb = EXP2(c1*D2(rd1, k));
        w0[k] = ea; s1a += ea;
        w1[k] = eb; s1b += eb;
      }
      dpp16_2(s1a, s1b);
      if ((lane & 15) == 0) {
        atomicAdd(&redf[(r + 1) % 3][0], s1a);
        atomicAdd(&redf[(r + 1) % 3][1], s1b);
      }
    }
  }
  #pragma unroll
  for (int k = 0; k < KC; ++k)
    atomicAdd(&g_cbuf[0][b*MPTS + t + TPB*k], colacc[k]);   // remainr == 1
  (void)wave;
}

// Fused [k_cols(l)] + C(level l) + A(level l+1).
// eq = exp2(cq*d2) is next level's exp; e1 = (eq^2)^2 (c1 = 4*cq exactly).
// LAST (l==8): next level coeff is 0 -> eq = 1.
template<bool LAST>
__global__ __launch_bounds__(TPB) void k_ca(float c1, float cq, int l) {
  const int blk = blockIdx.x, b = blk >> 7, chunk = blk & (CHUNKS-1);
  const int t = threadIdx.x, lane = t & 63, wave = t >> 6;
  const int rowbase = b*NPTS + chunk*RPB;
  const float* __restrict__ cs_in = g_cbuf[l % 3];
  float* __restrict__ cs_out  = g_cbuf[(l+1) % 3];
  float* __restrict__ cs_zero = g_cbuf[(l+2) % 3];
  const float* __restrict__ rr_in = g_rbuf[l & 1];
  float* __restrict__ rr_out = g_rbuf[(l+1) & 1];
  __shared__ float4 rowdat[RPB];
  __shared__ float  sc_s[RPB], rl_s[RPB];
  __shared__ float  redf[3][4];
  __shared__ float  cred[8];
  // column stage + folded k_cols (global writes gated to chunk==0)
  float cx[KC], cy[KC], cz[KC], rc2[KC], pp[KC], rrn[KC];
  #pragma unroll
  for (int k = 0; k < KC; ++k) {
    const int m = b*MPTS + t + TPB*k;
    const float4 q = g_gt4[m];
    cx[k] = q.x; cy[k] = q.y; cz[k] = q.z; rc2[k] = q.w;
    const float cs = cs_in[m], rrv = rr_in[m];
    const float ratio = fminf(rrv / (cs + 1e-9f), 1.0f);
    pp[k]  = rrv*ratio;
    rrn[k] = fmaxf(rrv - cs*ratio, 0.0f);
    if (chunk == 0) { rr_out[m] = rrn[k]; cs_zero[m] = 0.0f; }
  }
  if (t < RPB) {
    rowdat[t] = g_gen4[rowbase + t];
    sc_s[t] = g_s[rowbase + t];
    rl_s[t] = g_remainl[rowbase + t];
  }
  if (t < 12) ((float*)redf)[t] = 0.f;
  __syncthreads();
  float colacc[KC] = {0.f, 0.f, 0.f, 0.f};
  float costacc = 0.f;
  float w0[KC], w1[KC];

#define CA_ELEM(R0)                                                        \
  {                                                                        \
    const float4 rd0 = rowdat[R0], rd1 = rowdat[(R0)+1];                   \
    float s1a = 0.f, rsa = 0.f, s2a = 0.f;                                 \
    float s1b = 0.f, rsb = 0.f, s2b = 0.f;                                 \
    _Pragma("unroll")                                                      \
    for (int k = 0; k < KC; ++k) {                                         \
      const float d2a = D2(rd0, k), d2b = D2(rd1, k);                      \
      float e1a, wqa, e1b, wqb;                                            \
      if (LAST) {                                                          \
        e1a = EXP2(c1*d2a); wqa = rrn[k];                                  \
        e1b = EXP2(c1*d2b); wqb = rrn[k];                                  \
      } else {                                                             \
        const float eqa = EXP2(cq*d2a); const float q2a = eqa*eqa;         \
        e1a = q2a*q2a; wqa = eqa*rrn[k];                                   \
        const float eqb = EXP2(cq*d2b); const float q2b = eqb*eqb;         \
        e1b = q2b*q2b; wqb = eqb*rrn[k];                                   \
      }                                                                    \
      w0[k] = wqa; rsa += wqa;                                             \
      w1[k] = wqb; rsb += wqb;                                             \
      const float ua = e1a*pp[k], ub = e1b*pp[k];                          \
      s1a += ua; s1b += ub;                                                \
      s2a = fmaf(ua, FSQRT(fmaxf(d2a, 1e-20f)), s2a);                      \
      s2b = fmaf(ub, FSQRT(fmaxf(d2b, 1e-20f)), s2b);                      \
    }                                                                      \
    costacc = fmaf(sc_s[R0], s2a, costacc);                                \
    costacc = fmaf(sc_s[(R0)+1], s2b, costacc);                            \
    dpp16_4(s1a, rsa, s1b, rsb);                                           \
    if ((lane & 15) == 0) {                                                \
      float* rb = redf[(R0)/2 % 3];                                        \
      atomicAdd(&rb[0], s1a); atomicAdd(&rb[1], rsa);                      \
      atomicAdd(&rb[2], s1b); atomicAdd(&rb[3], rsb);                      \
    }                                                                      \
  }

  CA_ELEM(0)
  #pragma unroll 1
  for (int r = 0; r < NRND; ++r) {
    __syncthreads();
    const float s1t0 = redf[r % 3][0];
    const float rst0 = redf[r % 3][1];
    const float s1t1 = redf[r % 3][2];
    const float rst1 = redf[r % 3][3];
    if (t < 4) redf[(r + 2) % 3][t] = 0.f;
    const int r0 = 2*r, r1 = r0 + 1;
    const float rl0 = fmaxf(rl_s[r0] - sc_s[r0]*s1t0, 0.0f);
    const float rl1 = fmaxf(rl_s[r1] - sc_s[r1]*s1t1, 0.0f);
    const float scn0 = rl0 * RCP(rst0 + 1e-9f);
    const float scn1 = rl1 * RCP(rst1 + 1e-9f);
    if (t == 0) {
      g_remainl[rowbase + r0] = rl0;
      g_remainl[rowbase + r1] = rl1;
      g_s[rowbase + r0] = scn0;
      g_s[rowbase + r1] = scn1;
    }
    #pragma unroll
    for (int k = 0; k < KC; ++k)
      colacc[k] = fmaf(w0[k], scn0, fmaf(w1[k], scn1, colacc[k]));
    if (r + 1 < NRND) CA_ELEM(2*r + 2)
  }
#undef CA_ELEM
  #pragma unroll
  for (int k = 0; k < KC; ++k)
    atomicAdd(&cs_out[b*MPTS + t + TPB*k], colacc[k]);
  costacc = wsum_step1(costacc);
  if (lane == 0) cred[wave] = costacc;
  __syncthreads();
  if (t == 0) {
    float c = 0.f;
    #pragma unroll
    for (int ww = 0; ww < 8; ++ww) c += cred[ww];
    atomicAdd(&g_cost, c);
  }
}

// C-part of level 9 (coeff 0 -> weight = p): cost only, barrier-free loop.
// Reads colsum from cbuf[9%3=0], remainr from rbuf[9&1=1].
__global__ __launch_bounds__(TPB) void k_c_last() {
  const int blk = blockIdx.x, b = blk >> 7, chunk = blk & (CHUNKS-1);
  const int t = threadIdx.x, lane = t & 63, wave = t >> 6;
  const int rowbase = b*NPTS + chunk*RPB;
  const float* __restrict__ cs_in = g_cbuf[0];
  const float* __restrict__ rr_in = g_rbuf[1];
  __shared__ float4 rowdat[RPB];
  __shared__ float  sc_s[RPB];
  __shared__ float  cred[8];
  float cx[KC], cy[KC], cz[KC], rc2[KC], pp[KC];
  #pragma unroll
  for (int k = 0; k < KC; ++k) {
    const int m = b*MPTS + t + TPB*k;
    const float4 q = g_gt4[m];
    cx[k] = q.x; cy[k] = q.y; cz[k] = q.z; rc2[k] = q.w;
    const float cs = cs_in[m], rrv = rr_in[m];
    const float ratio = fminf(rrv / (cs + 1e-9f), 1.0f);
    pp[k] = rrv*ratio;
  }
  if (t < RPB) {
    rowdat[t] = g_gen4[rowbase + t];
    sc_s[t] = g_s[rowbase + t];
  }
  __syncthreads();
  float costacc = 0.f;
  #pragma unroll 1
  for (int r = 0; r < RPB; ++r) {
    const float4 rd = rowdat[r];
    float s2 = 0.f;
    #pragma unroll
    for (int k = 0; k < KC; ++k)
      s2 = fmaf(pp[k], FSQRT(fmaxf(D2(rd, k), 1e-20f)), s2);
    costacc = fmaf(sc_s[r], s2, costacc);
  }
  costacc = wsum_step1(costacc);
  if (lane == 0) cred[wave] = costacc;
  __syncthreads();
  if (t == 0) {
    float c = 0.f;
    #pragma unroll
    for (int ww = 0; ww < 8; ++ww) c += cred[ww];
    atomicAdd(&g_cost, c);
  }
}

__global__ void k_final(float* __restrict__ out) {
  out[0] = g_cost * (1.0f / (float)(BATCH*NPTS));
}

extern "C" void kernel_launch(void* const* d_in, const int* in_sizes, int n_in,
                              void* d_out, int out_size, void* d_ws, size_t ws_size,
                              hipStream_t stream) {
  const float* gen = (const float*)d_in[0];   // pc_gen [8,2048,3] f32
  const float* gt  = (const float*)d_in[1];   // pc_gt  [8,2048,3] f32
  float* out = (float*)d_out;

  const double L[10] = {-16384.0, -4096.0, -1024.0, -256.0, -64.0,
                        -16.0, -4.0, -1.0, -0.25, 0.0};
  float c[10];
  for (int i = 0; i < 10; ++i) c[i] = (float)(L[i] * 1.4426950408889634);

  k_init<<<64, 256, 0, stream>>>(gen, gt);
  k_a0<<<NBLK, TPB, 0, stream>>>(c[0]);
  for (int l = 0; l < 8; ++l)
    k_ca<false><<<NBLK, TPB, 0, stream>>>(c[l], c[l+1], l);
  k_ca<true><<<NBLK, TPB, 0, stream>>>(c[8], 0.f, 8);
  k_c_last<<<NBLK, TPB, 0, stream>>>();
  k_final<<<1, 1, 0, stream>>>(out);
}